// Round 3
// baseline (130.220 us; speedup 1.0000x reference)
//
#include <hip/hip_runtime.h>
#include <math.h>

// Problem constants
#define DIM   256
#define NST   256
#define LSEQ  512
#define BAT   2
#define DTSZ  64
#define PCOLS 576
#define NROWS 1024
#define NCH   8          // chunks per sequence (parallel-scan split)
#define LCH   64         // sequence steps per chunk (LSEQ/NCH)

constexpr float LOG2E = 1.4426950408889634f;

__device__ __forceinline__ float fexp2(float v) {
#if __has_builtin(__builtin_amdgcn_exp2f)
    return __builtin_amdgcn_exp2f(v);
#else
    return exp2f(v);
#endif
}

__device__ __forceinline__ float softplusf(float v) {
    return (v > 20.f) ? v : log1pf(__expf(v));
}

// LDS-only barrier: waits lgkmcnt(0) but leaves global (vmcnt) loads in flight.
__device__ __forceinline__ void barrier_lds_only() {
    __builtin_amdgcn_s_waitcnt(0xC07F);   // vmcnt=63, expcnt=7, lgkmcnt=0
    __builtin_amdgcn_s_barrier();
}

// Pack (beta, gamma) as bf16x2 in one dword: beta lo16, gamma hi16. RNE.
__device__ __forceinline__ unsigned pack_bg(float be, float ga) {
    unsigned ub = __float_as_uint(be);
    unsigned ug = __float_as_uint(ga);
    ub = (ub + 0x7fffu + ((ub >> 16) & 1u)) >> 16;
    ug = (ug + 0x7fffu + ((ug >> 16) & 1u)) & 0xffff0000u;
    return ub | ug;
}

// Wave-uniform register broadcast: read lane l of v (l uniform).
__device__ __forceinline__ float rdlane(float v, int l) {
    return __uint_as_float((unsigned)__builtin_amdgcn_readlane(
        (int)__float_as_uint(v), l));
}

// ---------------- proj v2 (unchanged from R2 — measured ≈ v1, kept for the
// fused epilogue + lower L2 traffic; this round changes only the scan).
__global__ __launch_bounds__(576) void proj_kernel(
    const float* __restrict__ x, const float* __restrict__ W_in,
    const float* __restrict__ W_dt, const float* __restrict__ b_dt,
    unsigned* __restrict__ betgam,     // [NROWS, NST] bf16x2
    float* __restrict__ dtp, float* __restrict__ dtxp)
{
    __shared__ float Ls[4][PCOLS];          // 9216 B
    const int tid  = threadIdx.x;           // == column in [0, 576)
    const int lane = tid & 63;
    const int r0   = blockIdx.x * 4;

    float vA[4][4];
    #pragma unroll
    for (int r = 0; r < 4; ++r) {
        #pragma unroll
        for (int q = 0; q < 4; ++q)
            vA[r][q] = x[(r0 + r) * DIM + q * 64 + lane];
    }

    float acc[4] = {0.f, 0.f, 0.f, 0.f};
    const float* wp = W_in + tid;
    #pragma unroll
    for (int q = 0; q < 4; ++q) {
        #pragma unroll 8
        for (int kl = 0; kl < 64; ++kl) {
            const float bw = wp[(q * 64 + kl) * PCOLS];
            #pragma unroll
            for (int r = 0; r < 4; ++r)
                acc[r] = fmaf(rdlane(vA[r][q], kl), bw, acc[r]);
        }
    }

    #pragma unroll
    for (int r = 0; r < 4; ++r) Ls[r][tid] = acc[r];
    __syncthreads();

    if (tid < 256) {
        const int d = tid;
        float vD[4];
        #pragma unroll
        for (int r = 0; r < 4; ++r) vD[r] = Ls[r][lane];

        const float bd = b_dt[d];
        float accd[4] = {bd, bd, bd, bd};
        const float* wdp = W_dt + d;
        #pragma unroll 8
        for (int k = 0; k < DTSZ; ++k) {
            const float wv = wdp[k * DIM];
            #pragma unroll
            for (int r = 0; r < 4; ++r)
                accd[r] = fmaf(rdlane(vD[r], k), wv, accd[r]);
        }
        #pragma unroll
        for (int r = 0; r < 4; ++r) {
            const int row = r0 + r;
            const float sp = softplusf(accd[r]);
            const float xv = x[row * DIM + d];
            dtp[row * DIM + d]  = sp;
            dtxp[row * DIM + d] = sp * xv;
        }
    } else if (tid < 512) {
        const int n = tid - 256;
        #pragma unroll
        for (int r = 0; r < 4; ++r) {
            const float be = Ls[r][64 + n];
            const float ga = Ls[r][320 + n];
            betgam[(r0 + r) * NST + n] = pack_bg(be, ga);
        }
    }
}

// ---------------- chunked scan, phase 1: per-chunk local scan from 0.
// Grid: BAT*DIM*NCH = 4096 blocks (16/CU queued, 4 waves/SIMD resident at
// launch_bounds(256,4)) — 8x the old 512-block parallelism, to convert the
// measured ~60% latency-stall (VALUBusy 44%, occ 17.7%) into issue time.
// Block = (b, d, chunk c). Writes S_c = chunk-local end state and the chunk
// dt-sum (A_c = exp2(aln*sumdt) is exact product of per-step gains).
// Block->XCD mapping: idx = d*16 + b*8 + c, so fixed (b,c) -> fixed XCD:
// each XCD's L2 holds only 2 chunks' betgam rows (128 KB) — high locality.
__global__ __launch_bounds__(256, 4) void scan_ph1(
    const float* __restrict__ alpha_log,    // [DIM, NST]
    const unsigned* __restrict__ betgam,    // [NROWS, NST] packed
    const float* __restrict__ dtp,          // [NROWS, DIM]
    const float* __restrict__ dtxp,         // [NROWS, DIM]
    float* __restrict__ Ssum,               // [B, D, NCH, NST]
    float* __restrict__ sumdt)              // [B, D, NCH]
{
    __shared__ float dts[LCH], dxs[LCH];
    const int n   = threadIdx.x;
    const int idx = blockIdx.x;
    const int d   = idx >> 4;
    const int b   = (idx >> 3) & 1;
    const int c   = idx & 7;
    const int rb  = b * LSEQ + c * LCH;     // first global row of this chunk

    if (n < LCH) {
        dts[n] = dtp [(rb + n) * DIM + d];
        dxs[n] = dtxp[(rb + n) * DIM + d];
    }
    const float aln = -__expf(alpha_log[d * NST + n]) * LOG2E;
    __syncthreads();

    // chunk dt-sum: wave 0 butterfly (parallel, no serial-LDS chain)
    if (n < 64) {
        float v = dts[n];
        v += __shfl_xor(v, 1);
        v += __shfl_xor(v, 2);
        v += __shfl_xor(v, 4);
        v += __shfl_xor(v, 8);
        v += __shfl_xor(v, 16);
        v += __shfl_xor(v, 32);
        if (n == 0) sumdt[(b * DIM + d) * NCH + c] = v;
    }

    float s = 0.f;
    unsigned bg[8][8];                      // full unroll -> static indices
    #pragma unroll
    for (int pw = 0; pw < 2; ++pw) {
        #pragma unroll
        for (int t = 0; t < 8; ++t)
            bg[pw][t] = betgam[(rb + pw * 8 + t) * NST + n];
    }

    #pragma unroll
    for (int w = 0; w < 8; ++w) {
        if (w + 2 < 8) {                    // 2-deep prefetch (TLP covers rest)
            #pragma unroll
            for (int t = 0; t < 8; ++t)
                bg[w + 2][t] = betgam[(rb + (w + 2) * 8 + t) * NST + n];
        }
        float4 dta = *(const float4*)&dts[w * 8];
        float4 dtb = *(const float4*)&dts[w * 8 + 4];
        float4 dxa = *(const float4*)&dxs[w * 8];
        float4 dxb = *(const float4*)&dxs[w * 8 + 4];
        const float dtw[8] = {dta.x, dta.y, dta.z, dta.w, dtb.x, dtb.y, dtb.z, dtb.w};
        const float dxw[8] = {dxa.x, dxa.y, dxa.z, dxa.w, dxb.x, dxb.y, dxb.z, dxb.w};
        #pragma unroll
        for (int t = 0; t < 8; ++t) {
            const unsigned u = bg[w][t];
            const float be = __uint_as_float(u << 16);
            float a = fexp2(dtw[t] * aln);
            s = fmaf(a, s, dxw[t] * be);
        }
    }
    Ssum[((b * DIM + d) * NCH + c) * NST + n] = s;
}

// ---------------- chunked scan, phase 2: combine chunk summaries.
// s0_c = state entering chunk c:  s0_0 = 0;  s0_c = S_{c-1} + A_{c-1}*s0_{c-1}.
// 512 blocks x 256 threads; ~16 VALU ops/thread — launch-overhead sized.
__global__ __launch_bounds__(256) void scan_comb(
    const float* __restrict__ alpha_log,
    const float* __restrict__ Ssum,         // [B, D, NCH, NST]
    const float* __restrict__ sumdt,        // [B, D, NCH]
    float* __restrict__ s0buf)              // [B, D, NCH, NST]
{
    const int n = threadIdx.x;
    const int d = blockIdx.x >> 1;
    const int b = blockIdx.x & 1;
    const float aln = -__expf(alpha_log[d * NST + n]) * LOG2E;
    const float* Sp  = Ssum  + (size_t)((b * DIM + d) * NCH) * NST + n;
    float*       s0p = s0buf + (size_t)((b * DIM + d) * NCH) * NST + n;
    const float* sdp = sumdt + (b * DIM + d) * NCH;
    float run = 0.f;
    #pragma unroll
    for (int c = 0; c < NCH; ++c) {
        s0p[c * NST] = run;
        run = fmaf(fexp2(aln * sdp[c]), run, Sp[c * NST]);
    }
}

// ---------------- chunked scan, phase 3: rescan each chunk from s0_c,
// with the gamma-reduction and output write. Same body as phase 1 plus
// the staged 16-row reduce (part padded +16 floats -> max 2-way banks,
// write side 2-way free, read side verified 2-way by construction).
__global__ __launch_bounds__(256, 4) void scan_ph3(
    const float* __restrict__ x,            // [NROWS, DIM]
    const float* __restrict__ alpha_log,    // [DIM, NST]
    const float* __restrict__ delta,        // [DIM]
    const unsigned* __restrict__ betgam,    // [NROWS, NST] packed
    const float* __restrict__ dtp,          // [NROWS, DIM]
    const float* __restrict__ dtxp,         // [NROWS, DIM]
    const float* __restrict__ s0buf,        // [B, D, NCH, NST]
    float* __restrict__ out)                // [NROWS, DIM]
{
    __shared__ float part[16][NST + 16];    // 17408 B, pad kills 4-way trow alias
    __shared__ float dts[LCH], dxs[LCH], xcol[LCH];
    const int n   = threadIdx.x;
    const int idx = blockIdx.x;
    const int d   = idx >> 4;
    const int b   = (idx >> 3) & 1;
    const int c   = idx & 7;
    const int rb  = b * LSEQ + c * LCH;

    if (n < LCH) {
        dts[n]  = dtp [(rb + n) * DIM + d];
        dxs[n]  = dtxp[(rb + n) * DIM + d];
        xcol[n] = x   [(rb + n) * DIM + d];
    }
    const float aln = -__expf(alpha_log[d * NST + n]) * LOG2E;
    const float dv  = delta[d];
    float s = s0buf[((size_t)(b * DIM + d) * NCH + c) * NST + n];
    __syncthreads();                        // staging dep (global->LDS)

    unsigned bg[8][8];
    #pragma unroll
    for (int pw = 0; pw < 2; ++pw) {
        #pragma unroll
        for (int t = 0; t < 8; ++t)
            bg[pw][t] = betgam[(rb + pw * 8 + t) * NST + n];
    }

    #pragma unroll
    for (int w = 0; w < 8; ++w) {
        if (w + 2 < 8) {
            #pragma unroll
            for (int t = 0; t < 8; ++t)
                bg[w + 2][t] = betgam[(rb + (w + 2) * 8 + t) * NST + n];
        }
        float4 dta = *(const float4*)&dts[w * 8];
        float4 dtb = *(const float4*)&dts[w * 8 + 4];
        float4 dxa = *(const float4*)&dxs[w * 8];
        float4 dxb = *(const float4*)&dxs[w * 8 + 4];
        const float dtw[8] = {dta.x, dta.y, dta.z, dta.w, dtb.x, dtb.y, dtb.z, dtb.w};
        const float dxw[8] = {dxa.x, dxa.y, dxa.z, dxa.w, dxb.x, dxb.y, dxb.z, dxb.w};

        const int prow = (w & 1) * 8;
        #pragma unroll
        for (int t = 0; t < 8; ++t) {
            const unsigned u = bg[w][t];
            const float be = __uint_as_float(u << 16);
            const float ga = __uint_as_float(u & 0xffff0000u);
            float a = fexp2(dtw[t] * aln);
            s = fmaf(a, s, dxw[t] * be);
            part[prow + t][n] = s * ga;     // 2-way bank alias: free
        }

        if (w & 1) {                        // every 16 steps: reduce 16 rows x 256
            barrier_lds_only();             // betgam prefetch stays in flight
            const int trow = n >> 4, seg = n & 15;
            float sum = 0.f;
            #pragma unroll
            for (int k = 0; k < 16; ++k)
                sum += part[trow][seg * 16 + ((k + n) & 15)];
            sum += __shfl_xor(sum, 1);
            sum += __shfl_xor(sum, 2);
            sum += __shfl_xor(sum, 4);
            sum += __shfl_xor(sum, 8);
            if (seg == 0) {
                const int ll = (w >> 1) * 16 + trow;    // local step in chunk
                out[(rb + ll) * DIM + d] = sum + xcol[ll] * dv;
            }
            barrier_lds_only();             // WAR before next window's writes
        }
    }
}

extern "C" void kernel_launch(void* const* d_in, const int* in_sizes, int n_in,
                              void* d_out, int out_size, void* d_ws, size_t ws_size,
                              hipStream_t stream) {
    const float* x         = (const float*)d_in[0];
    const float* W_in      = (const float*)d_in[1];
    const float* W_dt      = (const float*)d_in[2];
    const float* b_dt      = (const float*)d_in[3];
    const float* alpha_log = (const float*)d_in[4];
    const float* delta     = (const float*)d_in[5];
    float* out = (float*)d_out;

    // Workspace: betgam 1MB | dtp 1MB | dtxp 1MB | Ssum 4MB | s0buf 4MB | sumdt 16KB
    unsigned* betgam = (unsigned*)d_ws;
    float* dtp   = (float*)(betgam + NROWS * NST);
    float* dtxp  = dtp  + NROWS * DIM;
    float* Ssum  = dtxp + NROWS * DIM;
    float* s0buf = Ssum + BAT * DIM * NCH * NST;
    float* sumdt = s0buf + BAT * DIM * NCH * NST;

    proj_kernel<<<NROWS / 4, 576, 0, stream>>>(x, W_in, W_dt, b_dt, betgam, dtp, dtxp);
    scan_ph1 <<<BAT * DIM * NCH, 256, 0, stream>>>(alpha_log, betgam, dtp, dtxp, Ssum, sumdt);
    scan_comb<<<BAT * DIM,       256, 0, stream>>>(alpha_log, Ssum, sumdt, s0buf);
    scan_ph3 <<<BAT * DIM * NCH, 256, 0, stream>>>(x, alpha_log, delta, betgam, dtp, dtxp, s0buf, out);
}

// Round 4
// 111.289 us; speedup vs baseline: 1.1701x; 1.1701x over previous
//
#include <hip/hip_runtime.h>
#include <math.h>

// Problem constants
#define DIM   256
#define NST   256
#define LSEQ  512
#define BAT   2
#define DTSZ  64
#define PCOLS 576
#define NROWS 1024

typedef float    f32x4 __attribute__((ext_vector_type(4)));
typedef unsigned u32x4 __attribute__((ext_vector_type(4)));

constexpr float LOG2E = 1.4426950408889634f;

__device__ __forceinline__ float fexp2(float v) {
#if __has_builtin(__builtin_amdgcn_exp2f)
    return __builtin_amdgcn_exp2f(v);
#else
    return exp2f(v);
#endif
}

__device__ __forceinline__ float softplusf(float v) {
    return (v > 20.f) ? v : log1pf(__expf(v));
}

// LDS-only barrier: waits lgkmcnt(0) but leaves global (vmcnt) loads in flight.
__device__ __forceinline__ void barrier_lds_only() {
    __builtin_amdgcn_s_waitcnt(0xC07F);   // vmcnt=63, expcnt=7, lgkmcnt=0
    __builtin_amdgcn_s_barrier();
}

// Pack (beta, gamma) as bf16x2 in one dword: beta lo16, gamma hi16. RNE.
__device__ __forceinline__ unsigned pack_bg(float be, float ga) {
    unsigned ub = __float_as_uint(be);
    unsigned ug = __float_as_uint(ga);
    ub = (ub + 0x7fffu + ((ub >> 16) & 1u)) >> 16;
    ug = (ug + 0x7fffu + ((ug >> 16) & 1u)) & 0xffff0000u;
    return ub | ug;
}

// fp32 -> bf16 (RNE) as u16.
__device__ __forceinline__ unsigned short rne16(float f) {
    unsigned u = __float_as_uint(f);
    return (unsigned short)((u + 0x7fffu + ((u >> 16) & 1u)) >> 16);
}

// v_cvt_pk_bf16_f32: two fp32 -> packed bf16x2 (lo = src0, hi = src1), 1 instr.
__device__ __forceinline__ unsigned cvtpk(float lo, float hi) {
    unsigned r;
    asm("v_cvt_pk_bf16_f32 %0, %1, %2" : "=v"(r) : "v"(lo), "v"(hi));
    return r;
}

// MFMA via inline asm (robust against builtin signature differences; HK-style).
// D = A(16x32 bf16) * B(32x16 bf16) + C.  A: row=lane&15, k=(lane>>4)*8+i.
// B: col=lane&15, k=(lane>>4)*8+i.  C/D: col=lane&15, row=(lane>>4)*4+r.
__device__ __forceinline__ f32x4 mfma16(u32x4 a, u32x4 b, f32x4 c) {
    asm("v_mfma_f32_16x16x32_bf16 %0, %1, %2, %0" : "+v"(c) : "v"(a), "v"(b));
    return c;
}

// ---------------- proj_mfma: x@W_in via bf16 MFMA.
// Grid 288 = 32 row-tiles x 9 roles. Roles 0-7: matched (beta,gamma) strip
// pair cols {64+32j} / {320+32j} -> each lane holds beta AND gamma for the
// same n -> packs betgam locally (no races). Role 8: cols 0..63 -> dt_raw
// (fp32) to draw[]. B strips transposed fp32->bf16 into LDS (pad +8 u16:
// row stride 528B = 132 dw = 4 mod 32 banks -> 2-way on ds_read_b128).
// A loaded direct from x, converted in-regs via v_cvt_pk_bf16_f32.
__global__ __launch_bounds__(256) void proj_mfma(
    const float* __restrict__ x, const float* __restrict__ W_in,
    unsigned* __restrict__ betgam,     // [NROWS, NST] bf16x2
    float* __restrict__ draw)          // [NROWS, DTSZ] fp32 dt_raw
{
    __shared__ unsigned short Bt[64][264];   // 33792 B
    const int tid  = threadIdx.x;
    const int lane = tid & 63;
    const int mt   = blockIdx.x / 9;
    const int role = blockIdx.x % 9;

    // ---- stage B: 2 strips of 32 cols, transposed into LDS as [col][k]
    const int base0 = (role < 8) ? (64  + 32 * role) : 0;
    const int base1 = (role < 8) ? (320 + 32 * role) : 32;
    {
        const int cl = tid & 31;          // col within strip
        const int kq = tid >> 5;          // 0..7
        #pragma unroll 8
        for (int p = 0; p < 32; ++p) {
            const int k = p * 8 + kq;
            const float v0 = W_in[k * PCOLS + base0 + cl];
            const float v1 = W_in[k * PCOLS + base1 + cl];
            Bt[cl][k]      = rne16(v0);
            Bt[32 + cl][k] = rne16(v1);
        }
    }
    __syncthreads();

    const int w    = tid >> 6;
    const int wm   = w >> 1, wn = w & 1;
    const int row  = mt * 32 + wm * 16 + (lane & 15);
    const int koff = (lane >> 4) * 8;
    const float* xp = x + row * DIM + koff;
    const unsigned short* bp1 = &Bt[16 * wn + (lane & 15)][koff];
    const unsigned short* bp2 = &Bt[32 + 16 * wn + (lane & 15)][koff];

    f32x4 acc1 = {0.f, 0.f, 0.f, 0.f};
    f32x4 acc2 = {0.f, 0.f, 0.f, 0.f};
    #pragma unroll
    for (int kk = 0; kk < 8; ++kk) {     // K = 8 x 32
        const float4 xa = *(const float4*)(xp + kk * 32);
        const float4 xb = *(const float4*)(xp + kk * 32 + 4);
        u32x4 a;
        a.x = cvtpk(xa.x, xa.y);
        a.y = cvtpk(xa.z, xa.w);
        a.z = cvtpk(xb.x, xb.y);
        a.w = cvtpk(xb.z, xb.w);
        const u32x4 b1 = *(const u32x4*)(bp1 + kk * 32);
        const u32x4 b2 = *(const u32x4*)(bp2 + kk * 32);
        acc1 = mfma16(a, b1, acc1);
        acc2 = mfma16(a, b2, acc2);
    }

    const int rowbase = mt * 32 + wm * 16 + (lane >> 4) * 4;
    if (role < 8) {
        const int n = 32 * role + 16 * wn + (lane & 15);
        #pragma unroll
        for (int r = 0; r < 4; ++r)
            betgam[(rowbase + r) * NST + n] = pack_bg(acc1[r], acc2[r]);
    } else {
        const int c1 = 16 * wn + (lane & 15);
        #pragma unroll
        for (int r = 0; r < 4; ++r) {
            draw[(rowbase + r) * DTSZ + c1]      = acc1[r];
            draw[(rowbase + r) * DTSZ + 32 + c1] = acc2[r];
        }
    }
}

// ---------------- scan1p v3: R0's verified single-pass skeleton (main loop
// byte-identical), with the dt GEMM fused into the prologue: dts/dxs are
// computed in-block from draw (coalesced 256B rows) + W_dt column + softplus,
// replacing the 1KB-strided dtp/dtxp staged loads and the whole dt tail of
// the old proj kernel.
__global__ __launch_bounds__(256, 2) void scan1p(
    const float* __restrict__ x,            // [NROWS, DIM]
    const float* __restrict__ alpha_log,    // [DIM, NST]
    const float* __restrict__ delta,        // [DIM]
    const unsigned* __restrict__ betgam,    // [NROWS, NST] packed
    const float* __restrict__ draw,         // [NROWS, DTSZ]
    const float* __restrict__ W_dt,         // [DTSZ, DIM]
    const float* __restrict__ b_dt,         // [DIM]
    float* __restrict__ out)                // [NROWS, DIM]
{
    __shared__ float part[32][NST];         // 32 KB
    __shared__ float dts[LSEQ], dxs[LSEQ], xcol[LSEQ];   // 3 x 2 KB
    __shared__ float wdt[DTSZ];             // 256 B
    const int n = threadIdx.x;
    // XCD swizzle (R10-verified): XCDs 0-3 -> b=0, 4-7 -> b=1.
    const int xcd  = blockIdx.x & 7;
    const int slot = blockIdx.x >> 3;       // 0..63
    const int b = xcd >> 2;
    const int d = slot * 4 + (xcd & 3);
    const int rb = b * LSEQ;

    if (n < DTSZ) wdt[n] = W_dt[n * DIM + d];
    #pragma unroll
    for (int it = 0; it < 2; ++it) {
        const int l = n + it * 256;
        xcol[l] = x[(rb + l) * DIM + d];
    }
    const float aln = -__expf(alpha_log[d * NST + n]) * LOG2E;
    const float dv  = delta[d];
    const float bdv = b_dt[d];
    __syncthreads();                        // wdt/xcol ready

    // Fused dt GEMM: dts[l] = softplus(draw[rb+l,:] . wdt + b_dt[d])
    #pragma unroll
    for (int it = 0; it < 2; ++it) {
        const int l = n + it * 256;
        const float4* dr = (const float4*)&draw[(rb + l) * DTSZ];
        float acc = bdv;
        #pragma unroll
        for (int c = 0; c < 16; ++c) {
            const float4 v  = dr[c];
            const float4 wv = *(const float4*)&wdt[c * 4];
            acc = fmaf(v.x, wv.x, acc);
            acc = fmaf(v.y, wv.y, acc);
            acc = fmaf(v.z, wv.z, acc);
            acc = fmaf(v.w, wv.w, acc);
        }
        const float sp = softplusf(acc);
        dts[l] = sp;
        dxs[l] = sp * xcol[l];
    }
    __syncthreads();                        // dts/dxs ready

    float s = 0.f;
    unsigned bg[8][8];                      // 8-slot rotation, 6 windows ahead
    #pragma unroll
    for (int pw = 0; pw < 6; ++pw) {
        #pragma unroll
        for (int t = 0; t < 8; ++t)
            bg[pw][t] = betgam[(rb + pw * 8 + t) * NST + n];
    }

    #pragma unroll 8
    for (int w = 0; w < 64; ++w) {
        const int cur = w & 7;
        const int pf  = (w + 6) & 7;
        if (w + 6 < 64) {                   // issue window w+6 while computing w
            #pragma unroll
            for (int t = 0; t < 8; ++t)
                bg[pf][t] = betgam[(rb + (w + 6) * 8 + t) * NST + n];
        }
        float4 dta = *(const float4*)&dts[w * 8];
        float4 dtb = *(const float4*)&dts[w * 8 + 4];
        float4 dxa = *(const float4*)&dxs[w * 8];
        float4 dxb = *(const float4*)&dxs[w * 8 + 4];
        const float dtw[8] = {dta.x, dta.y, dta.z, dta.w, dtb.x, dtb.y, dtb.z, dtb.w};
        const float dxw[8] = {dxa.x, dxa.y, dxa.z, dxa.w, dxb.x, dxb.y, dxb.z, dxb.w};

        const int prow = (w & 3) * 8;
        #pragma unroll
        for (int t = 0; t < 8; ++t) {
            const unsigned u = bg[cur][t];
            const float be = __uint_as_float(u << 16);
            const float ga = __uint_as_float(u & 0xffff0000u);
            float a = fexp2(dtw[t] * aln);
            s = fmaf(a, s, dxw[t] * be);
            part[prow + t][n] = s * ga;     // 2-way bank alias: free
        }

        if ((w & 3) == 3) {                 // every 32 steps: reduce 32 rows x 256
            barrier_lds_only();
            const int trow = n >> 3, seg = n & 7;
            float sum = 0.f;
            #pragma unroll
            for (int k = 0; k < 32; ++k)
                sum += part[trow][seg * 32 + ((k + n) & 31)];   // measured 0-conflict
            sum += __shfl_xor(sum, 1);
            sum += __shfl_xor(sum, 2);
            sum += __shfl_xor(sum, 4);
            if (seg == 0) {
                const int l = (w >> 2) * 32 + trow;
                out[(rb + l) * DIM + d] = sum + xcol[l] * dv;
            }
            barrier_lds_only();             // WAR before next window's writes
        }
    }
}

extern "C" void kernel_launch(void* const* d_in, const int* in_sizes, int n_in,
                              void* d_out, int out_size, void* d_ws, size_t ws_size,
                              hipStream_t stream) {
    const float* x         = (const float*)d_in[0];
    const float* W_in      = (const float*)d_in[1];
    const float* W_dt      = (const float*)d_in[2];
    const float* b_dt      = (const float*)d_in[3];
    const float* alpha_log = (const float*)d_in[4];
    const float* delta     = (const float*)d_in[5];
    float* out = (float*)d_out;

    // Workspace: betgam 1MB | draw 256KB
    unsigned* betgam = (unsigned*)d_ws;
    float* draw = (float*)(betgam + NROWS * NST);

    proj_mfma<<<32 * 9, 256, 0, stream>>>(x, W_in, betgam, draw);
    scan1p<<<BAT * DIM, 256, 0, stream>>>(x, alpha_log, delta, betgam,
                                          draw, W_dt, b_dt, out);
}